// Round 10
// baseline (143.607 us; speedup 1.0000x reference)
//
#include <hip/hip_runtime.h>
#include <hip/hip_bf16.h>

// CIN (xDeepFM) fused 3-layer kernel for MI355X — R10: R9's algorithm
// (U-trick layer 2) restructured for 4 waves/SIMD occupancy.
// R9 post-mortem: MfmaUtil 31%, wall = 2 waves/SIMD can't cover per-wave
// stalls (chain-end MFMA latency, tail VALU, vmcnt). Occupancy is set by
// TOTAL regs (arch+AGPR, unified file, 512/SIMD): R9 = 128+64 = 192 -> 2
// waves/SIMD. Fix: one batch per wave (nt=1): sfr 64->32, W bufs 64->32,
// Y 32->16, outacc 32->16 => total ~115 <= 128 -> 4 waves/SIMD.
// WG = 1024 thr (16 waves), grid 256 = 1 WG/CU. Same per-CU MFMA count
// (6176/WG), same 20.6us floor, 2x the latency-hiding.
// Waves: L0/L1: (bw = w>>2: batch) x (mrow = w&3: h-tile of 32).
//        L2 step1: (bw) x (gt = w&3); step2: (kh = w>>2) x (mt = w&3),
//        4-way K-split with LDS partial reduce.
// Canary: WRITE_SIZE ~1.5MB = no spill. If it jumps, allocator lost.

typedef __attribute__((ext_vector_type(8))) short short8;
typedef __attribute__((ext_vector_type(8))) __bf16 bf16x8;
typedef __attribute__((ext_vector_type(16))) float f32x16;
typedef __attribute__((ext_vector_type(4))) unsigned short u16x4;

#define DEVINL static __device__ __forceinline__

DEVINL unsigned short f2bf_rne(float f) {
  unsigned int u = __builtin_bit_cast(unsigned int, f);
  unsigned int r = u + 0x7fffu + ((u >> 16) & 1u);
  return (unsigned short)(r >> 16);
}

// MFMA adapter: builtin may want v8i16 or v8bf16. SFINAE both.
template <typename V>
DEVINL auto mfma_32x32x16_bf16(V a, V b, f32x16 c, int)
    -> decltype(__builtin_amdgcn_mfma_f32_32x32x16_bf16(a, b, c, 0, 0, 0)) {
  return __builtin_amdgcn_mfma_f32_32x32x16_bf16(a, b, c, 0, 0, 0);
}
template <typename V>
DEVINL f32x16 mfma_32x32x16_bf16(V a, V b, f32x16 c, long) {
  return __builtin_amdgcn_mfma_f32_32x32x16_bf16(
      __builtin_bit_cast(bf16x8, a), __builtin_bit_cast(bf16x8, b), c, 0, 0, 0);
}
DEVINL f32x16 mfma_bf16(short8 a, short8 b, f32x16 c) {
  return mfma_32x32x16_bf16(a, b, c, 0);
}

// ---------------- W pack kernel (unchanged, verified R2-R9) ----------------
// Packed layout per layer: [f][kb=k>>3][h][j=k&7] bf16 (granule = 1024 u16).
__global__ void pack_w_kernel(const float* __restrict__ W0,
                              const float* __restrict__ W1,
                              const float* __restrict__ W2,
                              unsigned short* __restrict__ Wt) {
  __shared__ float tile[8][132];
  const int u = blockIdx.x;
  const float* W; int FK, f, kb, base;
  if (u < 128)      { W = W0; FK = 32;  f = u >> 2;         kb = u & 3;          base = 0; }
  else if (u < 640) { W = W1; FK = 128; f = (u - 128) >> 4; kb = (u - 128) & 15; base = 131072; }
  else              { W = W2; FK = 128; f = (u - 640) >> 4; kb = (u - 640) & 15; base = 655360; }
  const int t = threadIdx.x;
#pragma unroll
  for (int i = 0; i < 4; ++i) {
    const int e = t + i * 256;  // 0..1023
    const int kk = e >> 7, h = e & 127;
    tile[kk][h] = W[(f * FK + kb * 8 + kk) * 128 + h];
  }
  __syncthreads();
  unsigned short* dst = Wt + base + f * (FK / 8) * 1024 + kb * 1024;
  const int h = t >> 1;
  const int j0 = (t & 1) * 4;
  u16x4 v;
  v.x = f2bf_rne(tile[j0 + 0][h]);
  v.y = f2bf_rne(tile[j0 + 1][h]);
  v.z = f2bf_rne(tile[j0 + 2][h]);
  v.w = f2bf_rne(tile[j0 + 3][h]);
  *(u16x4*)&dst[t * 4] = v;
}

// ---------------- layers 0/1 (single batch per wave) ----------------
// Quad = 4 granule loads (16B/lane); addr gb + q*16384 + i*4096 bytes.
// KQ=8 (L1): field f = quads (2f, 2f+1); KQ=2 (L0): quad q = fields 2q,2q+1.
template <int KQ, int LAYER>
DEVINL void run_layer(const unsigned short* __restrict__ WtL,
                      const float* __restrict__ bias,
                      const float* __restrict__ x0g,
                      float* __restrict__ outp, int outoff,
                      unsigned int* SB,
                      int wgb0, int mrow, int bw, int l31, int half) {
  __syncthreads();  // state in SB ready (prologue or previous epilogue)

  // B-frags (S): slot (half,j) of sfr[kq] = S[r][k = kq*16 + half*8 + j],
  // r = bw*32 + l31 (batch bw, d = l31). SB row k2 packs (even lo, odd hi).
  int4 sfr[KQ];
  const int r = bw * 32 + l31;
#pragma unroll
  for (int kq = 0; kq < KQ; ++kq) {
    const int row0 = kq * 8 + half * 4;
    int4 v;
    v.x = (int)SB[(row0 + 0) * 128 + r];
    v.y = (int)SB[(row0 + 1) * 128 + r];
    v.z = (int)SB[(row0 + 2) * 128 + r];
    v.w = (int)SB[(row0 + 3) * 128 + r];
    sfr[kq] = v;
  }

  f32x16 zv;
#pragma unroll
  for (int e = 0; e < 16; ++e) zv[e] = 0.f;
  f32x16 outacc = zv;

  const char* gb = (const char*)WtL +
                   (size_t)(half * 2048 + (mrow * 32 + l31) * 16);
  const int xb = (wgb0 + bw) * 1024 + l31;  // x0[b][f][d=l31], +f*32

  auto ldq = [&](short8* wv, int q) {  // 4 granules of quad q
#pragma unroll
    for (int i = 0; i < 4; ++i)
      wv[i] = *(const short8*)(gb + (size_t)q * 16384 + i * 4096);
  };

  short8 wa[4], wb[4];

  if constexpr (KQ == 8) {
    float xs = x0g[xb];
    ldq(wa, 0);
    ldq(wb, 1);
    __syncthreads();  // all waves hold sfr; SB free for epilogue writes

#pragma unroll 1
    for (int f = 0; f < 32; ++f) {
      float xn = xs;
      if (f < 31) xn = x0g[xb + (f + 1) * 32];
      f32x16 Y;
#pragma unroll
      for (int i = 0; i < 4; ++i) {  // kq 0..3 (quad 2f)
        const short8 s = __builtin_bit_cast(short8, sfr[i]);
        Y = mfma_bf16(wa[i], s, i == 0 ? zv : Y);
      }
      if (f < 31) ldq(wa, 2 * f + 2);
#pragma unroll
      for (int i = 0; i < 4; ++i) {  // kq 4..7 (quad 2f+1)
        const short8 s = __builtin_bit_cast(short8, sfr[4 + i]);
        Y = mfma_bf16(wb[i], s, Y);
      }
      if (f < 31) ldq(wb, 2 * f + 3);
#pragma unroll
      for (int e = 0; e < 16; ++e) outacc[e] += xs * Y[e];
      xs = xn;
    }
  } else {
    // L0: quad q = fields (2q, 2q+1); wv[0],wv[1] = kq0,1 of field 2q;
    // wv[2],wv[3] = field 2q+1. Double-buffer, xs one quad ahead.
    float xa0 = x0g[xb], xa1 = x0g[xb + 32];
    ldq(wa, 0);
    __syncthreads();

    const short8 s0 = __builtin_bit_cast(short8, sfr[0]);
    const short8 s1 = __builtin_bit_cast(short8, sfr[KQ - 1]);
    auto doQ = [&](const short8* wv, float xA, float xB) {
      f32x16 Y = mfma_bf16(wv[0], s0, zv);
      Y = mfma_bf16(wv[1], s1, Y);
#pragma unroll
      for (int e = 0; e < 16; ++e) outacc[e] += xA * Y[e];
      Y = mfma_bf16(wv[2], s0, zv);
      Y = mfma_bf16(wv[3], s1, Y);
#pragma unroll
      for (int e = 0; e < 16; ++e) outacc[e] += xB * Y[e];
    };

#pragma unroll 1
    for (int q2 = 0; q2 < 8; ++q2) {
      const int q = 2 * q2;
      const float xm0 = x0g[xb + (2 * q + 2) * 32];
      const float xm1 = x0g[xb + (2 * q + 3) * 32];
      ldq(wb, q + 1);
      float xn0 = xa0, xn1 = xa1;
      if (q2 < 7) {
        xn0 = x0g[xb + (2 * q + 4) * 32];
        xn1 = x0g[xb + (2 * q + 5) * 32];
      }
      doQ(wa, xa0, xa1);
      if (q2 < 7) ldq(wa, q + 2);
      doQ(wb, xm0, xm1);
      xa0 = xn0; xa1 = xn1;
    }
  }

  // --- epilogue ---
  // C/D: col = lane&31 = d; row = (reg&3)+8*(reg>>2)+4*half = h (in 32-tile).
  float bv[16];
#pragma unroll
  for (int e = 0; e < 16; ++e)
    bv[e] = bias[mrow * 32 + (e & 3) + 8 * (e >> 2) + 4 * half];

  if constexpr (LAYER < 2) {
    // next state S'[r][h] = bf16(acc+bias), packed [h/2][r] u32 into SB
#pragma unroll
    for (int g = 0; g < 4; ++g) {
      const int h2 = mrow * 16 + 4 * g + 2 * half;
      const float v0 = outacc[4 * g + 0] + bv[4 * g + 0];
      const float v1 = outacc[4 * g + 1] + bv[4 * g + 1];
      const float v2 = outacc[4 * g + 2] + bv[4 * g + 2];
      const float v3 = outacc[4 * g + 3] + bv[4 * g + 3];
      SB[h2 * 128 + r] = (unsigned)f2bf_rne(v0) | ((unsigned)f2bf_rne(v1) << 16);
      SB[(h2 + 1) * 128 + r] =
          (unsigned)f2bf_rne(v2) | ((unsigned)f2bf_rne(v3) << 16);
    }
  }

  // final output: out[b, outoff+h] = sum_d acc + 32*bias (d = l31 lanes)
  float sv[16];
#pragma unroll
  for (int e = 0; e < 16; ++e) {
    float v = outacc[e];
    v += __shfl_xor(v, 1);
    v += __shfl_xor(v, 2);
    v += __shfl_xor(v, 4);
    v += __shfl_xor(v, 8);
    v += __shfl_xor(v, 16);
    sv[e] = v + 32.0f * bv[e];
  }
  if (l31 == 0) {
#pragma unroll
    for (int g = 0; g < 4; ++g) {
      const int h = mrow * 32 + 8 * g + 4 * half;
      float4 o = {sv[4 * g + 0], sv[4 * g + 1], sv[4 * g + 2], sv[4 * g + 3]};
      *(float4*)&outp[bw * 384 + outoff + h] = o;
    }
  }
}

// ---------------- layer 2, U-trick (16 waves) ----------------
// out2[b,h] = sum_k U[b,k]*W2[k,h] + 32*b2[h];  U[b,f*128+g] = x0_b . S2_b^T.
DEVINL void run_layer2_fast(const unsigned short* __restrict__ WtL,
                            const float* __restrict__ bias,
                            const float* __restrict__ x0g,
                            float* __restrict__ outp,
                            unsigned int* SB, int wgb0,
                            int w, int l31, int half, int tid) {
  __syncthreads();  // S2 in SB ready ([h/2][r=b*32+d] u32 bf16-pairs)

  f32x16 zv;
#pragma unroll
  for (int e = 0; e < 16; ++e) zv[e] = 0.f;

  // ---- step 1: U_b = x0_b (32f x 32d) . S2_b^T (32d x 128g) ----
  // wave w: batch bw = w>>2, g-tile gt = w&3 (one 32-g tile each).
  const int bw = w >> 2, gt = w & 3;
  short8 a1[2];  // A[m=f=l31][k=d slot (half,j)]
  {
    const float* xr = &x0g[(size_t)(wgb0 + bw) * 1024 + l31 * 32];
#pragma unroll
    for (int kq = 0; kq < 2; ++kq) {
      const int d0 = kq * 16 + half * 8;
      union { short8 v; unsigned short u[8]; } t;
#pragma unroll
      for (int j = 0; j < 8; ++j) t.u[j] = f2bf_rne(xr[d0 + j]);
      a1[kq] = t.v;
    }
  }
  short8 bfr[2];  // [kq]: B[k=d][n=g]: S2[b, g=gt*32+l31, d]
  {
    const int g = gt * 32 + l31;
    const unsigned int* row = &SB[(g >> 1) * 128 + bw * 32];
    const int sh = (g & 1) * 16;
#pragma unroll
    for (int kq = 0; kq < 2; ++kq) {
      const int d0 = kq * 16 + half * 8;
      union { short8 v; unsigned short u[8]; } t;
#pragma unroll
      for (int j = 0; j < 8; ++j)
        t.u[j] = (unsigned short)(row[d0 + j] >> sh);
      bfr[kq] = t.v;
    }
  }
  f32x16 ua = mfma_bf16(a1[0], bfr[0], zv);
  ua = mfma_bf16(a1[1], bfr[1], ua);
  __syncthreads();  // all waves done reading S2 from SB

  // ---- write U into SB as U32[k2 = k/2][b] (u16 writes; k = f*128+g) ----
  unsigned short* U16 = (unsigned short*)SB;
  {
    const int g = gt * 32 + l31;
#pragma unroll
    for (int reg = 0; reg < 16; ++reg) {
      const int f = (reg & 3) + 8 * (reg >> 2) + 4 * half;
      const int k = f * 128 + g;
      U16[(k >> 1) * 8 + bw * 2 + (k & 1)] = f2bf_rne(ua[reg]);
    }
  }
  __syncthreads();  // U ready

  // ---- step 2: D[m=h][n=b] = sum_k W2[k,h]*U[b,k] ----
  // wave: mt = w&3 (h-tile), kh = w>>2 (k quarter: 16 quads = 64 kq each).
  const int mt = w & 3, kh = w >> 2;
  const char* gb = (const char*)WtL +
                   (size_t)(half * 2048 + (mt * 32 + l31) * 16);
  const int bl = l31 & 3;  // lanes 4..31 duplicate b (cols unused)

  auto ldq2 = [&](short8* wv, int q) {  // quad q -> kq = 4q..4q+3
#pragma unroll
    for (int i = 0; i < 4; ++i)
      wv[i] = *(const short8*)(gb + (size_t)q * 16384 + i * 4096);
  };
  auto breadq = [&](short8* bv, int q) {  // B-frags for the 4 kq of quad q
#pragma unroll
    for (int i = 0; i < 4; ++i) {
      const int row0 = (q * 4 + i) * 8 + half * 4;
      int4 v;
      v.x = (int)SB[(row0 + 0) * 4 + bl];
      v.y = (int)SB[(row0 + 1) * 4 + bl];
      v.z = (int)SB[(row0 + 2) * 4 + bl];
      v.w = (int)SB[(row0 + 3) * 4 + bl];
      bv[i] = __builtin_bit_cast(short8, v);
    }
  };

  f32x16 acc0 = zv, acc1 = zv;
  short8 qa[4], qb[4], Ba[4], Bb[4];
  const int q0 = kh * 16;  // 16 quads per wave
  ldq2(qa, q0);
  breadq(Ba, q0);
#pragma unroll 1
  for (int qq = 0; qq < 8; ++qq) {
    const int q = q0 + 2 * qq;
    ldq2(qb, q + 1);
    breadq(Bb, q + 1);
#pragma unroll
    for (int i = 0; i < 4; ++i) acc0 = mfma_bf16(qa[i], Ba[i], acc0);
    if (qq < 7) {
      ldq2(qa, q + 2);
      breadq(Ba, q + 2);
    }
#pragma unroll
    for (int i = 0; i < 4; ++i) acc1 = mfma_bf16(qb[i], Bb[i], acc1);
  }
#pragma unroll
  for (int e = 0; e < 16; ++e) acc0[e] += acc1[e];

  __syncthreads();  // all waves done reading U from SB

  // ---- partials P[o = b*128 + h][kh] f32 into SB (8KB), then reduce ----
  float* P = (float*)SB;
  if (l31 < 4) {  // b = l31
#pragma unroll
    for (int reg = 0; reg < 16; ++reg) {
      const int h = mt * 32 + (reg & 3) + 8 * (reg >> 2) + 4 * half;
      P[(l31 * 128 + h) * 4 + kh] = acc0[reg];
    }
  }
  __syncthreads();
  if (tid < 512) {
    const int b = tid >> 7, h = tid & 127;
    const float v = P[tid * 4] + P[tid * 4 + 1] + P[tid * 4 + 2] +
                    P[tid * 4 + 3] + 32.0f * bias[h];
    outp[b * 384 + 256 + h] = v;
  }
}

__global__ __launch_bounds__(1024, 1) void cin_kernel(
    const float* __restrict__ x0g, const unsigned short* __restrict__ Wt,
    const float* __restrict__ b0, const float* __restrict__ b1,
    const float* __restrict__ b2, float* __restrict__ out) {
  __shared__ unsigned int SB[64 * 128];  // 32KB state / U / partials

  const int t = threadIdx.x;
  const int lane = t & 63;
  const int w = t >> 6;      // 0..15
  const int mrow = w & 3;    // h-tile of 32 (L0/L1)
  const int bw = w >> 2;     // batch (L0/L1)
  const int l31 = lane & 31, half = lane >> 5;
  const int wgb0 = blockIdx.x * 4;  // 4 batches per WG

  // prologue: S1 = bf16(x0^T) -> SB ([g/2][r] u32, r = b_local*32+d)
#pragma unroll
  for (int s = 0; s < 2; ++s) {
    const int i = t + s * 1024;  // 0..2047
    const int r = i & 127, g2 = i >> 7;
    const float* p = &x0g[(wgb0 + (r >> 5)) * 1024 + (2 * g2) * 32 + (r & 31)];
    SB[g2 * 128 + r] =
        (unsigned)f2bf_rne(p[0]) | ((unsigned)f2bf_rne(p[32]) << 16);
  }
  // ordering handled by the entry barrier in run_layer

  float* outp = out + (size_t)wgb0 * 384;
  run_layer<2, 0>(Wt, b0, x0g, outp, 0, SB, wgb0, mrow, bw, l31, half);
  run_layer<8, 1>(Wt + 131072, b1, x0g, outp, 128, SB,
                  wgb0, mrow, bw, l31, half);
  run_layer2_fast(Wt + 655360, b2, x0g, outp, SB, wgb0, w, l31, half, t);
}

extern "C" void kernel_launch(void* const* d_in, const int* in_sizes, int n_in,
                              void* d_out, int out_size, void* d_ws, size_t ws_size,
                              hipStream_t stream) {
  (void)in_sizes; (void)n_in; (void)out_size; (void)ws_size;
  const float* x0 = (const float*)d_in[0];
  const float* W0 = (const float*)d_in[1];
  const float* W1 = (const float*)d_in[2];
  const float* W2 = (const float*)d_in[3];
  const float* b0 = (const float*)d_in[4];
  const float* b1 = (const float*)d_in[5];
  const float* b2 = (const float*)d_in[6];
  unsigned short* Wt = (unsigned short*)d_ws;  // 2,359,296 B

  pack_w_kernel<<<1152, 256, 0, stream>>>(W0, W1, W2, Wt);
  // 256 WGs x 1024 thr = 1 WG/CU (16 waves, 4/SIMD)
  cin_kernel<<<256, 1024, 0, stream>>>(x0, Wt, b0, b1, b2, (float*)d_out);
}

// Round 11
// 135.130 us; speedup vs baseline: 1.0627x; 1.0627x over previous
//
#include <hip/hip_runtime.h>
#include <hip/hip_bf16.h>

// CIN (xDeepFM) fused 3-layer kernel for MI355X — R11: R9 (best, 70.7us main)
// with the per-field MFMA chain split in two (2x chain-ILP per wave).
// R10 post-mortem: 4 waves/SIMD with 1 chain each = same 4 chains/SIMD as
// R9's 2 waves x 2 chains, but 2x the L1 W-traffic (redundant loads scale
// with waves-per-mrow) -> regressed to 79.5us, partially L1-BW-bound.
// R11 keeps R9's shape (8 waves, 2 batches/wave, x2 L1 redundancy) and uses
// the 2-waves/SIMD register headroom (256 total/wave; R9 used ~192) to hold
// 4 independent Y chains per wave (Ya/Yb per batch, kq 0-3 / 4-7) ->
// 8 chains/SIMD. Tail: outacc += xs*(Ya+Yb). AGPR +32 -> ~224/wave total.
// Canary: WRITE_SIZE ~1.5MB = no spill.
// Algorithm (R9): L0/L1 transposed MFMA D[m=h][n=(b,d)] = sum_k W[k,h]S[r,k],
// A = W straight global->VGPR (L2-resident), B = S registers, x0 post-scale;
// L2 via U-trick: out2[b,h] = (x0_b . S2_b^T) @ W2 (Gram matrix, -33% MFMA).
// Grid: 256 WGs x 512 thr = 1 WG/CU, 8 waves = 2/SIMD.

typedef __attribute__((ext_vector_type(8))) short short8;
typedef __attribute__((ext_vector_type(8))) __bf16 bf16x8;
typedef __attribute__((ext_vector_type(16))) float f32x16;
typedef __attribute__((ext_vector_type(4))) unsigned short u16x4;

#define DEVINL static __device__ __forceinline__

DEVINL unsigned short f2bf_rne(float f) {
  unsigned int u = __builtin_bit_cast(unsigned int, f);
  unsigned int r = u + 0x7fffu + ((u >> 16) & 1u);
  return (unsigned short)(r >> 16);
}

// MFMA adapter: builtin may want v8i16 or v8bf16. SFINAE both.
template <typename V>
DEVINL auto mfma_32x32x16_bf16(V a, V b, f32x16 c, int)
    -> decltype(__builtin_amdgcn_mfma_f32_32x32x16_bf16(a, b, c, 0, 0, 0)) {
  return __builtin_amdgcn_mfma_f32_32x32x16_bf16(a, b, c, 0, 0, 0);
}
template <typename V>
DEVINL f32x16 mfma_32x32x16_bf16(V a, V b, f32x16 c, long) {
  return __builtin_amdgcn_mfma_f32_32x32x16_bf16(
      __builtin_bit_cast(bf16x8, a), __builtin_bit_cast(bf16x8, b), c, 0, 0, 0);
}
DEVINL f32x16 mfma_bf16(short8 a, short8 b, f32x16 c) {
  return mfma_32x32x16_bf16(a, b, c, 0);
}

// ---------------- W pack kernel (unchanged, verified R2-R10) ----------------
// Packed layout per layer: [f][kb=k>>3][h][j=k&7] bf16 (granule = 1024 u16).
__global__ void pack_w_kernel(const float* __restrict__ W0,
                              const float* __restrict__ W1,
                              const float* __restrict__ W2,
                              unsigned short* __restrict__ Wt) {
  __shared__ float tile[8][132];
  const int u = blockIdx.x;
  const float* W; int FK, f, kb, base;
  if (u < 128)      { W = W0; FK = 32;  f = u >> 2;         kb = u & 3;          base = 0; }
  else if (u < 640) { W = W1; FK = 128; f = (u - 128) >> 4; kb = (u - 128) & 15; base = 131072; }
  else              { W = W2; FK = 128; f = (u - 640) >> 4; kb = (u - 640) & 15; base = 655360; }
  const int t = threadIdx.x;
#pragma unroll
  for (int i = 0; i < 4; ++i) {
    const int e = t + i * 256;  // 0..1023
    const int kk = e >> 7, h = e & 127;
    tile[kk][h] = W[(f * FK + kb * 8 + kk) * 128 + h];
  }
  __syncthreads();
  unsigned short* dst = Wt + base + f * (FK / 8) * 1024 + kb * 1024;
  const int h = t >> 1;
  const int j0 = (t & 1) * 4;
  u16x4 v;
  v.x = f2bf_rne(tile[j0 + 0][h]);
  v.y = f2bf_rne(tile[j0 + 1][h]);
  v.z = f2bf_rne(tile[j0 + 2][h]);
  v.w = f2bf_rne(tile[j0 + 3][h]);
  *(u16x4*)&dst[t * 4] = v;
}

// ---------------- layers 0/1 (R9 structure, R11 chain split) ----------------
// Quad = 4 granule loads (16B/lane). Field f (KQ=8) = quads (2f, 2f+1).
// Per-lane granule addr: gb + q*16384 + i*4096 bytes (i = 0..3).
template <int KQ, int STEPS, int LAYER>
DEVINL void run_layer(const unsigned short* __restrict__ WtL,
                      const float* __restrict__ bias,
                      const float* __restrict__ x0g,
                      float* __restrict__ outp, int outoff,
                      unsigned int* SB,
                      int wgb0, int mrow, int npair, int l31, int half) {
  __syncthreads();  // state in SB ready (prologue or previous epilogue)

  // B-frags (S) from SB into registers, once per layer.
  // slot (half,j) of sfr[nt][kq] holds S[r][k = kq*16 + half*8 + j],
  // r = npair*64 + nt*32 + l31. SB row k2=k/2 packs (k even lo16, k odd hi16).
  int4 sfr[2][KQ];
  const int rb = npair * 64;
#pragma unroll
  for (int nt = 0; nt < 2; ++nt) {
    const int r = rb + nt * 32 + l31;
#pragma unroll
    for (int kq = 0; kq < KQ; ++kq) {
      const int row0 = kq * 8 + half * 4;
      int4 v;
      v.x = (int)SB[(row0 + 0) * 128 + r];
      v.y = (int)SB[(row0 + 1) * 128 + r];
      v.z = (int)SB[(row0 + 2) * 128 + r];
      v.w = (int)SB[(row0 + 3) * 128 + r];
      sfr[nt][kq] = v;
    }
  }

  f32x16 zv;
#pragma unroll
  for (int e = 0; e < 16; ++e) zv[e] = 0.f;
  f32x16 outacc[2] = {zv, zv};

  const char* gb = (const char*)WtL +
                   (size_t)(half * 2048 + (mrow * 32 + l31) * 16);
  const int xb0 = (wgb0 + npair * 2 + 0) * 1024 + l31;
  const int xb1 = (wgb0 + npair * 2 + 1) * 1024 + l31;

  auto ldq = [&](short8* wv, int q) {  // 4 granules of quad q
#pragma unroll
    for (int i = 0; i < 4; ++i)
      wv[i] = *(const short8*)(gb + (size_t)q * 16384 + i * 4096);
  };

  if constexpr (KQ == 8) {
    // field f = quads (2f, 2f+1); iteration = 2 fields, 4 quad bufs.
    short8 w0[4], w1[4], w2[4], w3[4];
    float xc00 = x0g[xb0], xc01 = x0g[xb1];
    float xc10 = x0g[xb0 + 32], xc11 = x0g[xb1 + 32];
    ldq(w0, 0);
    ldq(w1, 1);
    __syncthreads();  // all waves hold sfr; SB free for this layer's epilogue

    // R11: 4 independent chains of 4 MFMAs (Ya/Yc on qa = kq0-3, Yb/Yd on
    // qb = kq4-7, per batch) instead of 2 chains of 8 -> 8 chains/SIMD.
    auto doFld = [&](const short8* qa, const short8* qb, float xs0, float xs1) {
      f32x16 Ya, Yb, Yc, Yd;
#pragma unroll
      for (int i = 0; i < 4; ++i) {
        const short8 s0 = __builtin_bit_cast(short8, sfr[0][i]);
        const short8 s1 = __builtin_bit_cast(short8, sfr[1][i]);
        const short8 s0h = __builtin_bit_cast(short8, sfr[0][4 + i]);
        const short8 s1h = __builtin_bit_cast(short8, sfr[1][4 + i]);
        Ya = mfma_bf16(qa[i], s0, i == 0 ? zv : Ya);
        Yc = mfma_bf16(qa[i], s1, i == 0 ? zv : Yc);
        Yb = mfma_bf16(qb[i], s0h, i == 0 ? zv : Yb);
        Yd = mfma_bf16(qb[i], s1h, i == 0 ? zv : Yd);
      }
#pragma unroll
      for (int e = 0; e < 16; ++e) {
        outacc[0][e] += xs0 * (Ya[e] + Yb[e]);
        outacc[1][e] += xs1 * (Yc[e] + Yd[e]);
      }
    };

#pragma unroll 1
    for (int it = 0; it < 16; ++it) {
      const int f = 2 * it;
      float xn00 = xc00, xn01 = xc01, xn10 = xc10, xn11 = xc11;
      if (it < 15) {
        xn00 = x0g[xb0 + (f + 2) * 32]; xn01 = x0g[xb1 + (f + 2) * 32];
        xn10 = x0g[xb0 + (f + 3) * 32]; xn11 = x0g[xb1 + (f + 3) * 32];
      }
      ldq(w2, 4 * it + 2);
      ldq(w3, 4 * it + 3);
      doFld(w0, w1, xc00, xc01);
      if (it < 15) {
        ldq(w0, 4 * it + 4);
        ldq(w1, 4 * it + 5);
      }
      doFld(w2, w3, xc10, xc11);
      xc00 = xn00; xc01 = xn01; xc10 = xn10; xc11 = xn11;
    }
  } else {
    // L0 (KQ=2): quad q = fields (2q, 2q+1); double buffer, xs one quad ahead.
    short8 wa[4], wb[4];
    float xa0 = x0g[xb0], xa1 = x0g[xb1];
    float xa2 = x0g[xb0 + 32], xa3 = x0g[xb1 + 32];
    ldq(wa, 0);
    __syncthreads();

    const short8 s00 = __builtin_bit_cast(short8, sfr[0][0]);
    const short8 s01 = __builtin_bit_cast(short8, sfr[0][1]);
    const short8 s10 = __builtin_bit_cast(short8, sfr[1][0]);
    const short8 s11 = __builtin_bit_cast(short8, sfr[1][1]);
    auto doQ = [&](const short8* wv, float x0a, float x1a, float x0b,
                   float x1b) {
      f32x16 Y0 = mfma_bf16(wv[0], s00, zv);
      Y0 = mfma_bf16(wv[1], s01, Y0);
      f32x16 Y1 = mfma_bf16(wv[0], s10, zv);
      Y1 = mfma_bf16(wv[1], s11, Y1);
#pragma unroll
      for (int e = 0; e < 16; ++e) {
        outacc[0][e] += x0a * Y0[e];
        outacc[1][e] += x1a * Y1[e];
      }
      Y0 = mfma_bf16(wv[2], s00, zv);
      Y0 = mfma_bf16(wv[3], s01, Y0);
      Y1 = mfma_bf16(wv[2], s10, zv);
      Y1 = mfma_bf16(wv[3], s11, Y1);
#pragma unroll
      for (int e = 0; e < 16; ++e) {
        outacc[0][e] += x0b * Y0[e];
        outacc[1][e] += x1b * Y1[e];
      }
    };

#pragma unroll 1
    for (int q2 = 0; q2 < 8; ++q2) {
      const int q = 2 * q2;
      const float xm0 = x0g[xb0 + (2 * q + 2) * 32];
      const float xm1 = x0g[xb1 + (2 * q + 2) * 32];
      const float xm2 = x0g[xb0 + (2 * q + 3) * 32];
      const float xm3 = x0g[xb1 + (2 * q + 3) * 32];
      ldq(wb, q + 1);
      float xn0 = xa0, xn1 = xa1, xn2 = xa2, xn3 = xa3;
      if (q2 < 7) {
        xn0 = x0g[xb0 + (2 * q + 4) * 32];
        xn1 = x0g[xb1 + (2 * q + 4) * 32];
        xn2 = x0g[xb0 + (2 * q + 5) * 32];
        xn3 = x0g[xb1 + (2 * q + 5) * 32];
      }
      doQ(wa, xa0, xa1, xa2, xa3);
      if (q2 < 7) ldq(wa, q + 2);
      doQ(wb, xm0, xm1, xm2, xm3);
      xa0 = xn0; xa1 = xn1; xa2 = xn2; xa3 = xn3;
    }
  }

  // --- epilogue ---
  // C/D layout: col = lane&31 = n; row = (reg&3)+8*(reg>>2)+4*half = h.
  float bv[16];
#pragma unroll
  for (int e = 0; e < 16; ++e)
    bv[e] = bias[mrow * 32 + (e & 3) + 8 * (e >> 2) + 4 * half];

  if constexpr (LAYER < 2) {
    // next state S'[r][h] = bf16(acc+bias), packed [h/2][r] u32 into SB
#pragma unroll
    for (int nt = 0; nt < 2; ++nt) {
      const int r = rb + nt * 32 + l31;
#pragma unroll
      for (int g = 0; g < 4; ++g) {
        const int h2 = mrow * 16 + 4 * g + 2 * half;
        const float v0 = outacc[nt][4 * g + 0] + bv[4 * g + 0];
        const float v1 = outacc[nt][4 * g + 1] + bv[4 * g + 1];
        const float v2 = outacc[nt][4 * g + 2] + bv[4 * g + 2];
        const float v3 = outacc[nt][4 * g + 3] + bv[4 * g + 3];
        SB[h2 * 128 + r] =
            (unsigned)f2bf_rne(v0) | ((unsigned)f2bf_rne(v1) << 16);
        SB[(h2 + 1) * 128 + r] =
            (unsigned)f2bf_rne(v2) | ((unsigned)f2bf_rne(v3) << 16);
      }
    }
  }

  // final output: out[b, outoff+h] = sum_d acc + 32*bias (d = l31 lanes)
#pragma unroll
  for (int nt = 0; nt < 2; ++nt) {
    float sv[16];
#pragma unroll
    for (int e = 0; e < 16; ++e) {
      float v = outacc[nt][e];
      v += __shfl_xor(v, 1);
      v += __shfl_xor(v, 2);
      v += __shfl_xor(v, 4);
      v += __shfl_xor(v, 8);
      v += __shfl_xor(v, 16);
      sv[e] = v + 32.0f * bv[e];
    }
    if (l31 == 0) {
      const int b = npair * 2 + nt;
#pragma unroll
      for (int g = 0; g < 4; ++g) {
        const int h = mrow * 32 + 8 * g + 4 * half;
        float4 o = {sv[4 * g + 0], sv[4 * g + 1], sv[4 * g + 2], sv[4 * g + 3]};
        *(float4*)&outp[b * 384 + outoff + h] = o;
      }
    }
  }
}

// ---------------- layer 2, U-trick (unchanged from R9) ----------------
// out2[b,h] = sum_k U[b,k]*W2[k,h] + 32*b2[h];  U[b,f*128+g] = x0_b . S2_b^T.
DEVINL void run_layer2_fast(const unsigned short* __restrict__ WtL,
                            const float* __restrict__ bias,
                            const float* __restrict__ x0g,
                            float* __restrict__ outp,
                            unsigned int* SB, int wgb0,
                            int w, int l31, int half, int tid) {
  __syncthreads();  // S2 in SB ready ([g/2][r=b*32+d] u32 bf16-pairs)

  f32x16 zv;
#pragma unroll
  for (int e = 0; e < 16; ++e) zv[e] = 0.f;

  // ---- step 1: U = x0_b (32f x 32d) . S2_b^T (32d x 128g), MFMA M=f,N=g,K=d
  // wave w: batch bw = w>>1, g-half gh = w&1 (2 n-tiles of g).
  const int bw = w >> 1, gh = w & 1;
  short8 a1[2];  // A[m=f=l31][k=d slots], kq=0,1
  {
    const float* xr = &x0g[(size_t)((wgb0 + bw) * 32 + l31) * 32];
#pragma unroll
    for (int kq = 0; kq < 2; ++kq) {
      const int d0 = kq * 16 + half * 8;
      union { short8 v; unsigned short u[8]; } t;
#pragma unroll
      for (int j = 0; j < 8; ++j) t.u[j] = f2bf_rne(xr[d0 + j]);
      a1[kq] = t.v;
    }
  }
  short8 bfr[2][2];  // [nt][kq]: B[k=d][n=g]: S2[b, g, d]
#pragma unroll
  for (int nt = 0; nt < 2; ++nt) {
    const int g = gh * 64 + nt * 32 + l31;
    const unsigned int* row = &SB[(g >> 1) * 128 + bw * 32];
    const int sh = (g & 1) * 16;
#pragma unroll
    for (int kq = 0; kq < 2; ++kq) {
      const int d0 = kq * 16 + half * 8;
      union { short8 v; unsigned short u[8]; } t;
#pragma unroll
      for (int j = 0; j < 8; ++j)
        t.u[j] = (unsigned short)(row[d0 + j] >> sh);
      bfr[nt][kq] = t.v;
    }
  }
  f32x16 ua[2];
#pragma unroll
  for (int nt = 0; nt < 2; ++nt) {
    ua[nt] = mfma_bf16(a1[0], bfr[nt][0], zv);
    ua[nt] = mfma_bf16(a1[1], bfr[nt][1], ua[nt]);
  }
  __syncthreads();  // all waves done reading S2 from SB

  // ---- write U into SB as U32[k2 = k/2][b] (k = f*128+g; u16 writes) ----
  unsigned short* U16 = (unsigned short*)SB;
#pragma unroll
  for (int nt = 0; nt < 2; ++nt) {
    const int g = gh * 64 + nt * 32 + l31;
#pragma unroll
    for (int reg = 0; reg < 16; ++reg) {
      const int f = (reg & 3) + 8 * (reg >> 2) + 4 * half;
      const int k = f * 128 + g;
      U16[(k >> 1) * 8 + bw * 2 + (k & 1)] = f2bf_rne(ua[nt][reg]);
    }
  }
  __syncthreads();  // U ready

  // ---- step 2: D[m=h][n=b] = sum_k W2[k,h]*U[b,k]; wave: mt=w&3, kh=w>>2 ----
  const int mt = w & 3, kh = w >> 2;
  const char* gb = (const char*)WtL +
                   (size_t)(half * 2048 + (mt * 32 + l31) * 16);
  const int bl = l31 & 3;  // lanes 4..31 duplicate b (cols unused, bounds-safe)

  auto ldq2 = [&](short8* wv, int q) {  // quad q -> kq = 4q..4q+3
#pragma unroll
    for (int i = 0; i < 4; ++i)
      wv[i] = *(const short8*)(gb + (size_t)q * 16384 + i * 4096);
  };
  auto breadq = [&](short8* bv, int q) {  // B-frags for the 4 kq of quad q
#pragma unroll
    for (int i = 0; i < 4; ++i) {
      const int row0 = (q * 4 + i) * 8 + half * 4;
      int4 v;
      v.x = (int)SB[(row0 + 0) * 4 + bl];
      v.y = (int)SB[(row0 + 1) * 4 + bl];
      v.z = (int)SB[(row0 + 2) * 4 + bl];
      v.w = (int)SB[(row0 + 3) * 4 + bl];
      bv[i] = __builtin_bit_cast(short8, v);
    }
  };

  f32x16 acc0 = zv, acc1 = zv;
  short8 qa[4], qb[4], Ba[4], Bb[4];
  const int q0 = kh * 32;  // 32 quads = 128 kq per wave
  ldq2(qa, q0);
  breadq(Ba, q0);
#pragma unroll 1
  for (int qq = 0; qq < 16; ++qq) {
    const int q = q0 + 2 * qq;
    ldq2(qb, q + 1);
    breadq(Bb, q + 1);
#pragma unroll
    for (int i = 0; i < 4; ++i) acc0 = mfma_bf16(qa[i], Ba[i], acc0);
    if (qq < 15) {
      ldq2(qa, q + 2);
      breadq(Ba, q + 2);
    }
#pragma unroll
    for (int i = 0; i < 4; ++i) acc1 = mfma_bf16(qb[i], Bb[i], acc1);
  }
#pragma unroll
  for (int e = 0; e < 16; ++e) acc0[e] += acc1[e];

  __syncthreads();  // all waves done reading U from SB

  // ---- partials P[o = b*128 + h][kh] f32 into SB (4KB), then reduce ----
  float* P = (float*)SB;
  if (l31 < 4) {
#pragma unroll
    for (int reg = 0; reg < 16; ++reg) {
      const int h = mt * 32 + (reg & 3) + 8 * (reg >> 2) + 4 * half;
      P[(l31 * 128 + h) * 2 + kh] = acc0[reg];
    }
  }
  __syncthreads();
  {
    const int b = tid >> 7, h = tid & 127;  // tid 0..511 -> all outputs
    const float v = P[tid * 2] + P[tid * 2 + 1] + 32.0f * bias[h];
    outp[b * 384 + 256 + h] = v;
  }
}

__global__ __launch_bounds__(512, 1) void cin_kernel(
    const float* __restrict__ x0g, const unsigned short* __restrict__ Wt,
    const float* __restrict__ b0, const float* __restrict__ b1,
    const float* __restrict__ b2, float* __restrict__ out) {
  __shared__ unsigned int SB[64 * 128];  // 32KB state / U / partials

  const int t = threadIdx.x;
  const int lane = t & 63;
  const int w = t >> 6;      // 0..7
  const int mrow = w & 3;    // h-tile of 32 (L0/L1)
  const int npair = w >> 2;  // batch pair (L0/L1)
  const int l31 = lane & 31, half = lane >> 5;
  const int wgb0 = blockIdx.x * 4;  // 4 batches per WG

  // prologue: S1 = bf16(x0^T) -> SB ([g/2][r] u32, r = b_local*32+d)
#pragma unroll
  for (int s = 0; s < 4; ++s) {
    const int i = t + s * 512;  // 0..2047
    const int r = i & 127, g2 = i >> 7;
    const float* p = &x0g[(wgb0 + (r >> 5)) * 1024 + (2 * g2) * 32 + (r & 31)];
    SB[g2 * 128 + r] =
        (unsigned)f2bf_rne(p[0]) | ((unsigned)f2bf_rne(p[32]) << 16);
  }
  // ordering handled by the entry barrier in run_layer

  float* outp = out + (size_t)wgb0 * 384;
  run_layer<2, 8, 0>(Wt, b0, x0g, outp, 0, SB, wgb0, mrow, npair, l31, half);
  run_layer<8, 32, 1>(Wt + 131072, b1, x0g, outp, 128, SB,
                      wgb0, mrow, npair, l31, half);
  run_layer2_fast(Wt + 655360, b2, x0g, outp, SB, wgb0, w, l31, half, t);
}

extern "C" void kernel_launch(void* const* d_in, const int* in_sizes, int n_in,
                              void* d_out, int out_size, void* d_ws, size_t ws_size,
                              hipStream_t stream) {
  (void)in_sizes; (void)n_in; (void)out_size; (void)ws_size;
  const float* x0 = (const float*)d_in[0];
  const float* W0 = (const float*)d_in[1];
  const float* W1 = (const float*)d_in[2];
  const float* W2 = (const float*)d_in[3];
  const float* b0 = (const float*)d_in[4];
  const float* b1 = (const float*)d_in[5];
  const float* b2 = (const float*)d_in[6];
  unsigned short* Wt = (unsigned short*)d_ws;  // 2,359,296 B

  pack_w_kernel<<<1152, 256, 0, stream>>>(W0, W1, W2, Wt);
  // 256 WGs x 512 thr = 1 WG/CU (8 waves, 2/SIMD)
  cin_kernel<<<256, 512, 0, stream>>>(x0, Wt, b0, b1, b2, (float*)d_out);
}

// Round 12
// 130.735 us; speedup vs baseline: 1.0985x; 1.0336x over previous
//
#include <hip/hip_runtime.h>
#include <hip/hip_bf16.h>

// CIN (xDeepFM) fused 3-layer kernel for MI355X — R12: R9 (best verified,
// 70.7us main) + all x0/xs reads moved from global to LDS.
// R10/R11 post-mortem: not BW-bound (traffic +71% -> time +12%), not
// chain-latency-bound (8 vs 4 chains/SIMD: no change). ~70% of SIMD cycles
// are waits. Suspected: the in-order vmcnt queue — every K-loop iteration
// issues 4 scattered 128B xs loads BEFORE the W quad loads, so each
// s_waitcnt protecting W also waits on the slow xs loads; L2 step1 does 16
// scattered global reads/lane. Fix: stage the WG's x0 block (16KB) into LDS
// once (global_load_lds, 16B width), xs reads become ds_read (lgkmcnt — a
// SEPARATE counter) -> W vmcnt waits are pure, scattered loads vanish.
// Algorithm unchanged (R9): L0/L1 transposed MFMA D[m=h][n=(b,d)], A = W
// global->VGPR (L2-resident), B = S registers, x0 post-scale; L2 U-trick.
// Grid: 256 WGs x 512 thr = 1 WG/CU, 8 waves = 2/SIMD. LDS 48KB.

typedef __attribute__((ext_vector_type(8))) short short8;
typedef __attribute__((ext_vector_type(8))) __bf16 bf16x8;
typedef __attribute__((ext_vector_type(16))) float f32x16;
typedef __attribute__((ext_vector_type(4))) unsigned short u16x4;

#define DEVINL static __device__ __forceinline__

DEVINL unsigned short f2bf_rne(float f) {
  unsigned int u = __builtin_bit_cast(unsigned int, f);
  unsigned int r = u + 0x7fffu + ((u >> 16) & 1u);
  return (unsigned short)(r >> 16);
}

// async global->LDS, 16B per lane; LDS dest = wave-uniform base + lane*16
DEVINL void gload_lds16(const void* g, void* l) {
  __builtin_amdgcn_global_load_lds(
      (const __attribute__((address_space(1))) unsigned int*)g,
      (__attribute__((address_space(3))) unsigned int*)l, 16, 0, 0);
}

// MFMA adapter: builtin may want v8i16 or v8bf16. SFINAE both.
template <typename V>
DEVINL auto mfma_32x32x16_bf16(V a, V b, f32x16 c, int)
    -> decltype(__builtin_amdgcn_mfma_f32_32x32x16_bf16(a, b, c, 0, 0, 0)) {
  return __builtin_amdgcn_mfma_f32_32x32x16_bf16(a, b, c, 0, 0, 0);
}
template <typename V>
DEVINL f32x16 mfma_32x32x16_bf16(V a, V b, f32x16 c, long) {
  return __builtin_amdgcn_mfma_f32_32x32x16_bf16(
      __builtin_bit_cast(bf16x8, a), __builtin_bit_cast(bf16x8, b), c, 0, 0, 0);
}
DEVINL f32x16 mfma_bf16(short8 a, short8 b, f32x16 c) {
  return mfma_32x32x16_bf16(a, b, c, 0);
}

// ---------------- W pack kernel (unchanged, verified R2-R11) ----------------
// Packed layout per layer: [f][kb=k>>3][h][j=k&7] bf16 (granule = 1024 u16).
__global__ void pack_w_kernel(const float* __restrict__ W0,
                              const float* __restrict__ W1,
                              const float* __restrict__ W2,
                              unsigned short* __restrict__ Wt) {
  __shared__ float tile[8][132];
  const int u = blockIdx.x;
  const float* W; int FK, f, kb, base;
  if (u < 128)      { W = W0; FK = 32;  f = u >> 2;         kb = u & 3;          base = 0; }
  else if (u < 640) { W = W1; FK = 128; f = (u - 128) >> 4; kb = (u - 128) & 15; base = 131072; }
  else              { W = W2; FK = 128; f = (u - 640) >> 4; kb = (u - 640) & 15; base = 655360; }
  const int t = threadIdx.x;
#pragma unroll
  for (int i = 0; i < 4; ++i) {
    const int e = t + i * 256;  // 0..1023
    const int kk = e >> 7, h = e & 127;
    tile[kk][h] = W[(f * FK + kb * 8 + kk) * 128 + h];
  }
  __syncthreads();
  unsigned short* dst = Wt + base + f * (FK / 8) * 1024 + kb * 1024;
  const int h = t >> 1;
  const int j0 = (t & 1) * 4;
  u16x4 v;
  v.x = f2bf_rne(tile[j0 + 0][h]);
  v.y = f2bf_rne(tile[j0 + 1][h]);
  v.z = f2bf_rne(tile[j0 + 2][h]);
  v.w = f2bf_rne(tile[j0 + 3][h]);
  *(u16x4*)&dst[t * 4] = v;
}

// ---------------- layers 0/1 (R9 structure, xs from LDS) ----------------
// Quad = 4 granule loads (16B/lane). Field f (KQ=8) = quads (2f, 2f+1).
// Per-lane granule addr: gb + q*16384 + i*4096 bytes (i = 0..3).
template <int KQ, int STEPS, int LAYER>
DEVINL void run_layer(const unsigned short* __restrict__ WtL,
                      const float* __restrict__ bias,
                      const float* x0l,  // LDS-resident x0 block [b][f][d]
                      float* __restrict__ outp, int outoff,
                      unsigned int* SB,
                      int wgb0, int mrow, int npair, int l31, int half) {
  __syncthreads();  // state in SB + x0l ready (prologue or previous epilogue)

  // B-frags (S) from SB into registers, once per layer.
  // slot (half,j) of sfr[nt][kq] holds S[r][k = kq*16 + half*8 + j],
  // r = npair*64 + nt*32 + l31. SB row k2=k/2 packs (k even lo16, k odd hi16).
  int4 sfr[2][KQ];
  const int rb = npair * 64;
#pragma unroll
  for (int nt = 0; nt < 2; ++nt) {
    const int r = rb + nt * 32 + l31;
#pragma unroll
    for (int kq = 0; kq < KQ; ++kq) {
      const int row0 = kq * 8 + half * 4;
      int4 v;
      v.x = (int)SB[(row0 + 0) * 128 + r];
      v.y = (int)SB[(row0 + 1) * 128 + r];
      v.z = (int)SB[(row0 + 2) * 128 + r];
      v.w = (int)SB[(row0 + 3) * 128 + r];
      sfr[nt][kq] = v;
    }
  }

  f32x16 zv;
#pragma unroll
  for (int e = 0; e < 16; ++e) zv[e] = 0.f;
  f32x16 outacc[2] = {zv, zv};

  const char* gb = (const char*)WtL +
                   (size_t)(half * 2048 + (mrow * 32 + l31) * 16);
  const int xb0 = (npair * 2 + 0) * 1024 + l31;  // x0l[b_local][f][d=l31]
  const int xb1 = (npair * 2 + 1) * 1024 + l31;

  auto ldq = [&](short8* wv, int q) {  // 4 granules of quad q
#pragma unroll
    for (int i = 0; i < 4; ++i)
      wv[i] = *(const short8*)(gb + (size_t)q * 16384 + i * 4096);
  };

  if constexpr (KQ == 8) {
    // field f = quads (2f, 2f+1); iteration = 2 fields, 4 quad bufs.
    short8 w0[4], w1[4], w2[4], w3[4];
    float xc00 = x0l[xb0], xc01 = x0l[xb1];
    float xc10 = x0l[xb0 + 32], xc11 = x0l[xb1 + 32];
    ldq(w0, 0);
    ldq(w1, 1);
    __syncthreads();  // all waves hold sfr; SB free for this layer's epilogue

    auto doFld = [&](const short8* qa, const short8* qb, float xs0, float xs1) {
      f32x16 Y0, Y1;
#pragma unroll
      for (int i = 0; i < 4; ++i) {
        const short8 s0 = __builtin_bit_cast(short8, sfr[0][i]);
        const short8 s1 = __builtin_bit_cast(short8, sfr[1][i]);
        Y0 = mfma_bf16(qa[i], s0, i == 0 ? zv : Y0);
        Y1 = mfma_bf16(qa[i], s1, i == 0 ? zv : Y1);
      }
#pragma unroll
      for (int i = 0; i < 4; ++i) {
        const short8 s0 = __builtin_bit_cast(short8, sfr[0][4 + i]);
        const short8 s1 = __builtin_bit_cast(short8, sfr[1][4 + i]);
        Y0 = mfma_bf16(qb[i], s0, Y0);
        Y1 = mfma_bf16(qb[i], s1, Y1);
      }
#pragma unroll
      for (int e = 0; e < 16; ++e) {
        outacc[0][e] += xs0 * Y0[e];
        outacc[1][e] += xs1 * Y1[e];
      }
    };

#pragma unroll 1
    for (int it = 0; it < 16; ++it) {
      const int f = 2 * it;
      float xn00 = xc00, xn01 = xc01, xn10 = xc10, xn11 = xc11;
      if (it < 15) {  // LDS reads (lgkmcnt) — do not touch the vmcnt queue
        xn00 = x0l[xb0 + (f + 2) * 32]; xn01 = x0l[xb1 + (f + 2) * 32];
        xn10 = x0l[xb0 + (f + 3) * 32]; xn11 = x0l[xb1 + (f + 3) * 32];
      }
      ldq(w2, 4 * it + 2);
      ldq(w3, 4 * it + 3);
      doFld(w0, w1, xc00, xc01);
      if (it < 15) {
        ldq(w0, 4 * it + 4);
        ldq(w1, 4 * it + 5);
      }
      doFld(w2, w3, xc10, xc11);
      xc00 = xn00; xc01 = xn01; xc10 = xn10; xc11 = xn11;
    }
  } else {
    // L0 (KQ=2): quad q = fields (2q, 2q+1); double buffer, xs one quad ahead.
    short8 wa[4], wb[4];
    float xa0 = x0l[xb0], xa1 = x0l[xb1];
    float xa2 = x0l[xb0 + 32], xa3 = x0l[xb1 + 32];
    ldq(wa, 0);
    __syncthreads();

    const short8 s00 = __builtin_bit_cast(short8, sfr[0][0]);
    const short8 s01 = __builtin_bit_cast(short8, sfr[0][1]);
    const short8 s10 = __builtin_bit_cast(short8, sfr[1][0]);
    const short8 s11 = __builtin_bit_cast(short8, sfr[1][1]);
    auto doQ = [&](const short8* wv, float x0a, float x1a, float x0b,
                   float x1b) {
      f32x16 Y0 = mfma_bf16(wv[0], s00, zv);
      Y0 = mfma_bf16(wv[1], s01, Y0);
      f32x16 Y1 = mfma_bf16(wv[0], s10, zv);
      Y1 = mfma_bf16(wv[1], s11, Y1);
#pragma unroll
      for (int e = 0; e < 16; ++e) {
        outacc[0][e] += x0a * Y0[e];
        outacc[1][e] += x1a * Y1[e];
      }
      Y0 = mfma_bf16(wv[2], s00, zv);
      Y0 = mfma_bf16(wv[3], s01, Y0);
      Y1 = mfma_bf16(wv[2], s10, zv);
      Y1 = mfma_bf16(wv[3], s11, Y1);
#pragma unroll
      for (int e = 0; e < 16; ++e) {
        outacc[0][e] += x0b * Y0[e];
        outacc[1][e] += x1b * Y1[e];
      }
    };

#pragma unroll 1
    for (int q2 = 0; q2 < 8; ++q2) {
      const int q = 2 * q2;
      const float xm0 = x0l[xb0 + (2 * q + 2) * 32];
      const float xm1 = x0l[xb1 + (2 * q + 2) * 32];
      const float xm2 = x0l[xb0 + (2 * q + 3) * 32];
      const float xm3 = x0l[xb1 + (2 * q + 3) * 32];
      ldq(wb, q + 1);
      float xn0 = xa0, xn1 = xa1, xn2 = xa2, xn3 = xa3;
      if (q2 < 7) {
        xn0 = x0l[xb0 + (2 * q + 4) * 32];
        xn1 = x0l[xb1 + (2 * q + 4) * 32];
        xn2 = x0l[xb0 + (2 * q + 5) * 32];
        xn3 = x0l[xb1 + (2 * q + 5) * 32];
      }
      doQ(wa, xa0, xa1, xa2, xa3);
      if (q2 < 7) ldq(wa, q + 2);
      doQ(wb, xm0, xm1, xm2, xm3);
      xa0 = xn0; xa1 = xn1; xa2 = xn2; xa3 = xn3;
    }
  }

  // --- epilogue ---
  // C/D layout: col = lane&31 = n; row = (reg&3)+8*(reg>>2)+4*half = h.
  float bv[16];
#pragma unroll
  for (int e = 0; e < 16; ++e)
    bv[e] = bias[mrow * 32 + (e & 3) + 8 * (e >> 2) + 4 * half];

  if constexpr (LAYER < 2) {
    // next state S'[r][h] = bf16(acc+bias), packed [h/2][r] u32 into SB
#pragma unroll
    for (int nt = 0; nt < 2; ++nt) {
      const int r = rb + nt * 32 + l31;
#pragma unroll
      for (int g = 0; g < 4; ++g) {
        const int h2 = mrow * 16 + 4 * g + 2 * half;
        const float v0 = outacc[nt][4 * g + 0] + bv[4 * g + 0];
        const float v1 = outacc[nt][4 * g + 1] + bv[4 * g + 1];
        const float v2 = outacc[nt][4 * g + 2] + bv[4 * g + 2];
        const float v3 = outacc[nt][4 * g + 3] + bv[4 * g + 3];
        SB[h2 * 128 + r] =
            (unsigned)f2bf_rne(v0) | ((unsigned)f2bf_rne(v1) << 16);
        SB[(h2 + 1) * 128 + r] =
            (unsigned)f2bf_rne(v2) | ((unsigned)f2bf_rne(v3) << 16);
      }
    }
  }

  // final output: out[b, outoff+h] = sum_d acc + 32*bias (d = l31 lanes)
#pragma unroll
  for (int nt = 0; nt < 2; ++nt) {
    float sv[16];
#pragma unroll
    for (int e = 0; e < 16; ++e) {
      float v = outacc[nt][e];
      v += __shfl_xor(v, 1);
      v += __shfl_xor(v, 2);
      v += __shfl_xor(v, 4);
      v += __shfl_xor(v, 8);
      v += __shfl_xor(v, 16);
      sv[e] = v + 32.0f * bv[e];
    }
    if (l31 == 0) {
      const int b = npair * 2 + nt;
#pragma unroll
      for (int g = 0; g < 4; ++g) {
        const int h = mrow * 32 + 8 * g + 4 * half;
        float4 o = {sv[4 * g + 0], sv[4 * g + 1], sv[4 * g + 2], sv[4 * g + 3]};
        *(float4*)&outp[b * 384 + outoff + h] = o;
      }
    }
  }
}

// ---------------- layer 2, U-trick (R9; x0 from LDS) ----------------
// out2[b,h] = sum_k U[b,k]*W2[k,h] + 32*b2[h];  U[b,f*128+g] = x0_b . S2_b^T.
DEVINL void run_layer2_fast(const unsigned short* __restrict__ WtL,
                            const float* __restrict__ bias,
                            const float* x0l,
                            float* __restrict__ outp,
                            unsigned int* SB, int wgb0,
                            int w, int l31, int half, int tid) {
  __syncthreads();  // S2 in SB ready ([g/2][r=b*32+d] u32 bf16-pairs)

  f32x16 zv;
#pragma unroll
  for (int e = 0; e < 16; ++e) zv[e] = 0.f;

  // ---- step 1: U = x0_b (32f x 32d) . S2_b^T (32d x 128g), MFMA M=f,N=g,K=d
  // wave w: batch bw = w>>1, g-half gh = w&1 (2 n-tiles of g).
  const int bw = w >> 1, gh = w & 1;
  short8 a1[2];  // A[m=f=l31][k=d slots], kq=0,1  (reads from LDS x0l)
  {
    const float* xr = &x0l[bw * 1024 + l31 * 32];
#pragma unroll
    for (int kq = 0; kq < 2; ++kq) {
      const int d0 = kq * 16 + half * 8;
      union { short8 v; unsigned short u[8]; } t;
#pragma unroll
      for (int j = 0; j < 8; ++j) t.u[j] = f2bf_rne(xr[d0 + j]);
      a1[kq] = t.v;
    }
  }
  short8 bfr[2][2];  // [nt][kq]: B[k=d][n=g]: S2[b, g, d]
#pragma unroll
  for (int nt = 0; nt < 2; ++nt) {
    const int g = gh * 64 + nt * 32 + l31;
    const unsigned int* row = &SB[(g >> 1) * 128 + bw * 32];
    const int sh = (g & 1) * 16;
#pragma unroll
    for (int kq = 0; kq < 2; ++kq) {
      const int d0 = kq * 16 + half * 8;
      union { short8 v; unsigned short u[8]; } t;
#pragma unroll
      for (int j = 0; j < 8; ++j)
        t.u[j] = (unsigned short)(row[d0 + j] >> sh);
      bfr[nt][kq] = t.v;
    }
  }
  f32x16 ua[2];
#pragma unroll
  for (int nt = 0; nt < 2; ++nt) {
    ua[nt] = mfma_bf16(a1[0], bfr[nt][0], zv);
    ua[nt] = mfma_bf16(a1[1], bfr[nt][1], ua[nt]);
  }
  __syncthreads();  // all waves done reading S2 from SB

  // ---- write U into SB as U32[k2 = k/2][b] (k = f*128+g; u16 writes) ----
  unsigned short* U16 = (unsigned short*)SB;
#pragma unroll
  for (int nt = 0; nt < 2; ++nt) {
    const int g = gh * 64 + nt * 32 + l31;
#pragma unroll
    for (int reg = 0; reg < 16; ++reg) {
      const int f = (reg & 3) + 8 * (reg >> 2) + 4 * half;
      const int k = f * 128 + g;
      U16[(k >> 1) * 8 + bw * 2 + (k & 1)] = f2bf_rne(ua[nt][reg]);
    }
  }
  __syncthreads();  // U ready

  // ---- step 2: D[m=h][n=b] = sum_k W2[k,h]*U[b,k]; wave: mt=w&3, kh=w>>2 ----
  const int mt = w & 3, kh = w >> 2;
  const char* gb = (const char*)WtL +
                   (size_t)(half * 2048 + (mt * 32 + l31) * 16);
  const int bl = l31 & 3;  // lanes 4..31 duplicate b (cols unused, bounds-safe)

  auto ldq2 = [&](short8* wv, int q) {  // quad q -> kq = 4q..4q+3
#pragma unroll
    for (int i = 0; i < 4; ++i)
      wv[i] = *(const short8*)(gb + (size_t)q * 16384 + i * 4096);
  };
  auto breadq = [&](short8* bv, int q) {  // B-frags for the 4 kq of quad q
#pragma unroll
    for (int i = 0; i < 4; ++i) {
      const int row0 = (q * 4 + i) * 8 + half * 4;
      int4 v;
      v.x = (int)SB[(row0 + 0) * 4 + bl];
      v.y = (int)SB[(row0 + 1) * 4 + bl];
      v.z = (int)SB[(row0 + 2) * 4 + bl];
      v.w = (int)SB[(row0 + 3) * 4 + bl];
      bv[i] = __builtin_bit_cast(short8, v);
    }
  };

  f32x16 acc0 = zv, acc1 = zv;
  short8 qa[4], qb[4], Ba[4], Bb[4];
  const int q0 = kh * 32;  // 32 quads = 128 kq per wave
  ldq2(qa, q0);
  breadq(Ba, q0);
#pragma unroll 1
  for (int qq = 0; qq < 16; ++qq) {
    const int q = q0 + 2 * qq;
    ldq2(qb, q + 1);
    breadq(Bb, q + 1);
#pragma unroll
    for (int i = 0; i < 4; ++i) acc0 = mfma_bf16(qa[i], Ba[i], acc0);
    if (qq < 15) {
      ldq2(qa, q + 2);
      breadq(Ba, q + 2);
    }
#pragma unroll
    for (int i = 0; i < 4; ++i) acc1 = mfma_bf16(qb[i], Bb[i], acc1);
  }
#pragma unroll
  for (int e = 0; e < 16; ++e) acc0[e] += acc1[e];

  __syncthreads();  // all waves done reading U from SB

  // ---- partials P[o = b*128 + h][kh] f32 into SB (4KB), then reduce ----
  float* P = (float*)SB;
  if (l31 < 4) {
#pragma unroll
    for (int reg = 0; reg < 16; ++reg) {
      const int h = mt * 32 + (reg & 3) + 8 * (reg >> 2) + 4 * half;
      P[(l31 * 128 + h) * 2 + kh] = acc0[reg];
    }
  }
  __syncthreads();
  {
    const int b = tid >> 7, h = tid & 127;  // tid 0..511 -> all outputs
    const float v = P[tid * 2] + P[tid * 2 + 1] + 32.0f * bias[h];
    outp[b * 384 + 256 + h] = v;
  }
}

__global__ __launch_bounds__(512, 1) void cin_kernel(
    const float* __restrict__ x0g, const unsigned short* __restrict__ Wt,
    const float* __restrict__ b0, const float* __restrict__ b1,
    const float* __restrict__ b2, float* __restrict__ out) {
  __shared__ unsigned int SB[64 * 128];  // 32KB state / U / partials
  __shared__ __align__(16) float x0l[4096];  // 16KB x0 block [b][f][d]

  const int t = threadIdx.x;
  const int lane = t & 63;
  const int w = t >> 6;      // 0..7
  const int mrow = w & 3;    // h-tile of 32 (L0/L1)
  const int npair = w >> 2;  // batch pair (L0/L1)
  const int l31 = lane & 31, half = lane >> 5;
  const int wgb0 = blockIdx.x * 4;  // 4 batches per WG

  // prologue A: stage x0 block -> LDS via global_load_lds (16 chunks x 1KB)
  const float* xsrc = x0g + (size_t)wgb0 * 1024;
#pragma unroll
  for (int c = 0; c < 2; ++c) {
    const int chunk = w * 2 + c;
    gload_lds16(xsrc + chunk * 256 + lane * 4, x0l + chunk * 256);
  }
  // prologue B: S1 = bf16(x0^T) -> SB ([g/2][r] u32, r = b_local*32+d)
#pragma unroll
  for (int s = 0; s < 4; ++s) {
    const int i = t + s * 512;  // 0..2047
    const int r = i & 127, g2 = i >> 7;
    const float* p = &x0g[(wgb0 + (r >> 5)) * 1024 + (2 * g2) * 32 + (r & 31)];
    SB[g2 * 128 + r] =
        (unsigned)f2bf_rne(p[0]) | ((unsigned)f2bf_rne(p[32]) << 16);
  }
  // visibility handled by the entry barrier in run_layer (full drain)

  float* outp = out + (size_t)wgb0 * 384;
  run_layer<2, 8, 0>(Wt, b0, x0l, outp, 0, SB, wgb0, mrow, npair, l31, half);
  run_layer<8, 32, 1>(Wt + 131072, b1, x0l, outp, 128, SB,
                      wgb0, mrow, npair, l31, half);
  run_layer2_fast(Wt + 655360, b2, x0l, outp, SB, wgb0, w, l31, half, t);
}

extern "C" void kernel_launch(void* const* d_in, const int* in_sizes, int n_in,
                              void* d_out, int out_size, void* d_ws, size_t ws_size,
                              hipStream_t stream) {
  (void)in_sizes; (void)n_in; (void)out_size; (void)ws_size;
  const float* x0 = (const float*)d_in[0];
  const float* W0 = (const float*)d_in[1];
  const float* W1 = (const float*)d_in[2];
  const float* W2 = (const float*)d_in[3];
  const float* b0 = (const float*)d_in[4];
  const float* b1 = (const float*)d_in[5];
  const float* b2 = (const float*)d_in[6];
  unsigned short* Wt = (unsigned short*)d_ws;  // 2,359,296 B

  pack_w_kernel<<<1152, 256, 0, stream>>>(W0, W1, W2, Wt);
  // 256 WGs x 512 thr = 1 WG/CU (8 waves, 2/SIMD)
  cin_kernel<<<256, 512, 0, stream>>>(x0, Wt, b0, b1, b2, (float*)d_out);
}